// Round 6
// baseline (701.541 us; speedup 1.0000x reference)
//
#include <hip/hip_runtime.h>
#include <hip/hip_bf16.h>

// PPI GAT, 3 layers. N=50000, E=800000 (+N self loops), avg degree ~17.
// R6: dedicated skinny GEMM for layer-3 (32-row tiles, A direct-from-global,
//     B-only LDS; fixes 8%-occupancy bottleneck), uint4 aggS gathers.

#define NODES 50000
#define EDGES 800000
#define MPAD  50048            // ceil(N/128)*128
#define C0    25088            // layer-3 chunk-0 rows
#define C1    24912            // layer-3 chunk-1 rows

typedef unsigned short u16;
typedef __attribute__((ext_vector_type(8))) short bf16x8;
typedef __attribute__((ext_vector_type(4))) float f32x4;

__device__ __forceinline__ float bf16f(u16 r) {
    return __uint_as_float(((unsigned)r) << 16);
}
__device__ __forceinline__ u16 f2b(float v) {
    __hip_bfloat16 b = __float2bfloat16(v);
    return *(u16*)&b;
}
__device__ __forceinline__ float blo(unsigned d) { return __uint_as_float(d << 16); }
__device__ __forceinline__ float bhi(unsigned d) { return __uint_as_float(d & 0xffff0000u); }

// ---------------- CSR build ----------------

__global__ void fill_ones_kernel(int* __restrict__ deg, int n) {
    int i = blockIdx.x * blockDim.x + threadIdx.x;
    if (i < n) deg[i] = 1;  // self-loop
}

__global__ void hist_kernel(const int* __restrict__ dst, int* __restrict__ deg, int E) {
    int e = blockIdx.x * blockDim.x + threadIdx.x;
    if (e < E) atomicAdd(&deg[dst[e]], 1);
}

__global__ void deg_bsum_kernel(const int* __restrict__ deg, int* __restrict__ bsum, int n) {
    int tid = threadIdx.x, lane = tid & 63, wid = tid >> 6;
    int i = blockIdx.x * 256 + tid;
    int v = (i < n) ? deg[i] : 0;
    #pragma unroll
    for (int ofs = 32; ofs > 0; ofs >>= 1) v += __shfl_down(v, ofs);
    __shared__ int sp[4];
    if (lane == 0) sp[wid] = v;
    __syncthreads();
    if (tid == 0) bsum[blockIdx.x] = sp[0] + sp[1] + sp[2] + sp[3];
}

__global__ void bsum_scan_kernel(int* __restrict__ bsum, int* __restrict__ row_ptr,
                                 int nb, int n) {
    int tid = threadIdx.x, lane = tid & 63, wid = tid >> 6;
    int v = (tid < nb) ? bsum[tid] : 0;
    int incl = v;
    #pragma unroll
    for (int ofs = 1; ofs < 64; ofs <<= 1) {
        int t = __shfl_up(incl, ofs);
        if (lane >= ofs) incl += t;
    }
    __shared__ int sp[4];
    if (lane == 63) sp[wid] = incl;
    __syncthreads();
    int add = 0;
    for (int k = 0; k < wid; k++) add += sp[k];
    int excl = incl - v + add;
    if (tid < nb) bsum[tid] = excl;
    if (tid == nb - 1) row_ptr[n] = excl + v;
}

__global__ void deg_scan_kernel(const int* __restrict__ deg, const int* __restrict__ bofs,
                                int* __restrict__ row_ptr, int* __restrict__ cursor, int n) {
    int tid = threadIdx.x, lane = tid & 63, wid = tid >> 6;
    int i = blockIdx.x * 256 + tid;
    int v = (i < n) ? deg[i] : 0;
    int incl = v;
    #pragma unroll
    for (int ofs = 1; ofs < 64; ofs <<= 1) {
        int t = __shfl_up(incl, ofs);
        if (lane >= ofs) incl += t;
    }
    __shared__ int sp[4];
    if (lane == 63) sp[wid] = incl;
    __syncthreads();
    int add = bofs[blockIdx.x];
    for (int k = 0; k < wid; k++) add += sp[k];
    int excl = incl - v + add;
    if (i < n) { row_ptr[i] = excl; cursor[i] = excl; }
}

__global__ void scatter_kernel(const int* __restrict__ src, const int* __restrict__ dst,
                               int E, int n, int* __restrict__ cursor, int* __restrict__ csr_src) {
    int e = blockIdx.x * blockDim.x + threadIdx.x;
    if (e < E) {
        int d = dst[e];
        int p = atomicAdd(&cursor[d], 1);
        csr_src[p] = src[e];
    } else if (e < E + n) {
        int i = e - E;
        int p = atomicAdd(&cursor[i], 1);
        csr_src[p] = i;  // self-loop
    }
}

// ---------------- converts ----------------

__global__ void convertA4_kernel(const float* __restrict__ A, u16* __restrict__ O, int total4) {
    int idx = blockIdx.x * blockDim.x + threadIdx.x;
    if (idx >= total4) return;
    float4 f = ((const float4*)A)[idx];
    ushort4 o;
    o.x = f2b(f.x); o.y = f2b(f.y); o.z = f2b(f.z); o.w = f2b(f.w);
    ((ushort4*)O)[idx] = o;
}

__global__ void convertW_kernel(const float* __restrict__ W, int ldw, int col0,
                                int Ncols, int Npad, int K, u16* __restrict__ WT) {
    int idx = blockIdx.x * blockDim.x + threadIdx.x;
    if (idx >= Npad * K) return;
    int k = idx % K;
    int n = idx / K;
    float f = (n < Ncols) ? W[(size_t)k * ldw + col0 + n] : 0.f;
    WT[(size_t)n * K + k] = f2b(f);
}

__global__ void convertW3stack_kernel(const float* __restrict__ W3, u16* __restrict__ WT) {
    int idx = blockIdx.x * blockDim.x + threadIdx.x;
    if (idx >= 128 * 1536) return;
    int q = idx % 1536;
    int n = idx / 1536;
    int h = q >> 8, k = q & 255;
    float f = (n < 121) ? W3[(size_t)k * 726 + h * 121 + n] : 0.f;
    WT[(size_t)n * 1536 + q] = f2b(f);
}

// cm[o, k] (fp32): o<6 -> sum_c W3[k,h*121+c]*a3_src[h,c] (h=o); o in 6..11 -> a3_dst (h=o-6)
__global__ void prep_cmat_kernel(const float* __restrict__ W3, const float* __restrict__ a3s,
                                 const float* __restrict__ a3d, float* __restrict__ cm) {
    int idx = blockIdx.x * blockDim.x + threadIdx.x;
    if (idx >= 12 * 256) return;
    int k = idx & 255;
    int o = idx >> 8;
    int h = (o < 6) ? o : o - 6;
    const float* a = (o < 6) ? a3s : a3d;
    float v = 0.f;
    for (int c = 0; c < 121; c++) v += W3[(size_t)k * 726 + h * 121 + c] * a[h * 121 + c];
    cm[(size_t)o * 256 + k] = v;
}

// ---------------- bf16 MFMA GEMM (square-ish): C = A @ B^T, bf16 out, col split ----------------

__global__ __launch_bounds__(256) void gemm_mfma_kernel(
    const u16* __restrict__ A, const u16* __restrict__ B,
    u16* __restrict__ Cb, u16* __restrict__ Cb2,
    int M, int Ncols, int K2, int ldc, int split) {
    __shared__ __align__(16) u16 As[128][40];
    __shared__ __align__(16) u16 Bs[128][40];
    int tid = threadIdx.x;
    int lane = tid & 63;
    int wv = tid >> 6;
    int quad = lane >> 4, lm = lane & 15;
    int wm = (wv & 1) * 64, wn = (wv >> 1) * 64;
    int bm = blockIdx.x * 128, bn = blockIdx.y * 128;

    f32x4 zero = {0.f, 0.f, 0.f, 0.f};
    f32x4 acc[4][4];
    #pragma unroll
    for (int i = 0; i < 4; i++)
        #pragma unroll
        for (int j = 0; j < 4; j++) acc[i][j] = zero;

    for (int k0 = 0; k0 < K2; k0 += 32) {
        #pragma unroll
        for (int it = 0; it < 2; ++it) {
            int chunk = tid + it * 256;
            int row = chunk >> 2, seg = chunk & 3;
            uint4 va = *(const uint4*)(A + (size_t)(bm + row) * K2 + k0 + seg * 8);
            uint4 vb = *(const uint4*)(B + (size_t)(bn + row) * K2 + k0 + seg * 8);
            *(uint4*)&As[row][seg * 8] = va;
            *(uint4*)&Bs[row][seg * 8] = vb;
        }
        __syncthreads();
        bf16x8 af[4], bfr[4];
        #pragma unroll
        for (int i = 0; i < 4; i++) af[i] = *(const bf16x8*)&As[wm + i * 16 + lm][quad * 8];
        #pragma unroll
        for (int j = 0; j < 4; j++) bfr[j] = *(const bf16x8*)&Bs[wn + j * 16 + lm][quad * 8];
        #pragma unroll
        for (int i = 0; i < 4; i++)
            #pragma unroll
            for (int j = 0; j < 4; j++)
                acc[i][j] = __builtin_amdgcn_mfma_f32_16x16x32_bf16(af[i], bfr[j], acc[i][j], 0, 0, 0);
        __syncthreads();
    }

    // C/D layout: col = lane&15, row = quad*4 + reg
    #pragma unroll
    for (int i = 0; i < 4; i++) {
        #pragma unroll
        for (int j = 0; j < 4; j++) {
            int col = bn + wn + j * 16 + lm;
            if (col >= Ncols) continue;
            int row_base = bm + wm + i * 16 + quad * 4;
            #pragma unroll
            for (int r = 0; r < 4; r++) {
                int row = row_base + r;
                if (row >= M) continue;
                float v = acc[i][j][r];
                if (col < split) Cb[(size_t)row * ldc + col] = f2b(v);
                else             Cb2[(size_t)row * ldc + col - split] = f2b(v);
            }
        }
    }
}

// ---------------- skinny GEMM (layer 3): C[count,121] = A[count,1536] @ B[128,1536]^T ----
// 32-row x 128-col block tile; 4 waves: wave wv -> rows (wv>>1)*16, cols (wv&1)*64.
// A fragments direct from global (wave-private rows); B via LDS (L2-resident).
// Epilogue: sigmoid(v + bias[col]), fp32 out ld=121.

__global__ __launch_bounds__(256) void gemm_skinny(
    const u16* __restrict__ A, const u16* __restrict__ B,
    float* __restrict__ C, const float* __restrict__ bias, int count) {
    __shared__ __align__(16) u16 Bs[128][40];
    int tid = threadIdx.x, lane = tid & 63, wv = tid >> 6;
    int quad = lane >> 4, lm = lane & 15;
    int bm = blockIdx.x * 32;
    int mrow = (wv >> 1) * 16;
    int ncol = (wv & 1) * 64;
    int arow = bm + mrow + lm;
    if (arow >= count) arow = count - 1;  // clamped garbage; stores guarded
    const u16* Ap = A + (size_t)arow * 1536;

    f32x4 zero = {0.f, 0.f, 0.f, 0.f};
    f32x4 acc[4];
    #pragma unroll
    for (int j = 0; j < 4; j++) acc[j] = zero;

    for (int k0 = 0; k0 < 1536; k0 += 32) {
        #pragma unroll
        for (int it = 0; it < 2; ++it) {
            int chunk = tid + it * 256;
            int r = chunk >> 2, s = chunk & 3;
            *(uint4*)&Bs[r][s * 8] = *(const uint4*)(B + (size_t)r * 1536 + k0 + s * 8);
        }
        bf16x8 af = *(const bf16x8*)(Ap + k0 + quad * 8);
        __syncthreads();
        #pragma unroll
        for (int j = 0; j < 4; j++) {
            bf16x8 bf = *(const bf16x8*)&Bs[ncol + j * 16 + lm][quad * 8];
            acc[j] = __builtin_amdgcn_mfma_f32_16x16x32_bf16(af, bf, acc[j], 0, 0, 0);
        }
        __syncthreads();
    }

    #pragma unroll
    for (int j = 0; j < 4; j++) {
        int col = ncol + j * 16 + lm;
        if (col >= 121) continue;
        int row_base = bm + mrow + quad * 4;
        #pragma unroll
        for (int r = 0; r < 4; r++) {
            int row = row_base + r;
            if (row >= count) continue;
            float v = acc[j][r] + bias[col];
            v = 1.f / (1.f + __expf(-v));
            C[(size_t)row * 121 + col] = v;
        }
    }
}

// ---------------- attention logits, layers 1&2 ----------------

__global__ void row_alpha4_kernel(const u16* __restrict__ f, const float* __restrict__ a_s,
                                  const float* __restrict__ a_d, float* __restrict__ al_s,
                                  float* __restrict__ al_d, int n) {
    int wv = threadIdx.x >> 6, lane = threadIdx.x & 63;
    int i = blockIdx.x * 4 + wv;
    if (i >= n) return;
    ushort4 hv = *(const ushort4*)(f + (size_t)i * 256 + lane * 4);
    float4 as = *(const float4*)(a_s + lane * 4);
    float4 ad = *(const float4*)(a_d + lane * 4);
    float x0 = bf16f(hv.x), x1 = bf16f(hv.y), x2 = bf16f(hv.z), x3 = bf16f(hv.w);
    float ps = x0 * as.x + x1 * as.y + x2 * as.z + x3 * as.w;
    float pd = x0 * ad.x + x1 * ad.y + x2 * ad.z + x3 * ad.w;
    #pragma unroll
    for (int ofs = 1; ofs < 16; ofs <<= 1) {
        ps += __shfl_xor(ps, ofs);
        pd += __shfl_xor(pd, ofs);
    }
    if ((lane & 15) == 0) {
        int hd = lane >> 4;
        al_s[(size_t)i * 4 + hd] = ps;
        al_d[(size_t)i * 4 + hd] = pd;
    }
}

// layer-3 logits: al3[i, 0..5] = o2b[i]·cm_src, al3[i, 6..11] = o2b[i]·cm_dst
__global__ __launch_bounds__(256) void al3_kernel(const u16* __restrict__ o2b,
                                                  const float* __restrict__ cm,
                                                  float* __restrict__ al3, int n) {
    int wid = threadIdx.x >> 6, lane = threadIdx.x & 63;
    int i = blockIdx.x * 4 + wid;
    if (i >= n) return;
    uint2 d = *(const uint2*)(o2b + (size_t)i * 256 + lane * 4);
    float v0 = blo(d.x), v1 = bhi(d.x), v2 = blo(d.y), v3 = bhi(d.y);
    float a[12];
    #pragma unroll
    for (int o = 0; o < 12; o++) {
        float4 c = *(const float4*)(cm + (size_t)o * 256 + lane * 4);
        a[o] = v0 * c.x + v1 * c.y + v2 * c.z + v3 * c.w;
    }
    #pragma unroll
    for (int ofs = 1; ofs < 64; ofs <<= 1) {
        #pragma unroll
        for (int o = 0; o < 12; o++) a[o] += __shfl_xor(a[o], ofs);
    }
    if (lane == 0) {
        float4* dst = (float4*)(al3 + (size_t)i * 12);
        dst[0] = make_float4(a[0], a[1], a[2], a[3]);
        dst[1] = make_float4(a[4], a[5], a[6], a[7]);
        dst[2] = make_float4(a[8], a[9], a[10], a[11]);
    }
}

// ---------------- fused softmax+agg, layers 1&2: WAVE per node ----------------

__global__ __launch_bounds__(256) void agg4_fused(
    const u16* __restrict__ f, const float* __restrict__ al_s, const float* __restrict__ al_d,
    const int* __restrict__ row_ptr, const int* __restrict__ csr_src,
    const float* __restrict__ bias, const u16* __restrict__ resb,
    u16* __restrict__ outb, int n) {
    int wid = threadIdx.x >> 6, lane = threadIdx.x & 63;
    int i = blockIdx.x * 4 + wid;
    if (i >= n) return;
    int beg = row_ptr[i], end = row_ptr[i + 1];
    int h_st = lane >> 4;        // staging head
    int el = lane & 15;          // staging edge slot
    int half = lane >> 5;        // edge parity
    int c8 = (lane & 31) * 8;    // this lane's 8 channels
    float ald_st = al_d[(size_t)i * 4 + h_st];
    float acc[8] = {};
    float S = 0.f;
    for (int base = beg; base < end; base += 16) {
        int cnt = min(16, end - base);
        int idxv = csr_src[base + min(el, cnt - 1)];
        float av = al_s[(size_t)idxv * 4 + h_st] + ald_st;
        av = av > 0.f ? av : 0.2f * av;
        float ex = __expf(fminf(av, 60.f));
        for (int e = 0; e < cnt; e += 2) {
            int ei = e + half;
            int eu = ei < cnt ? ei : e;
            int s = __shfl(idxv, eu);
            float w = __shfl(ex, ((lane & 24) << 1) | eu);
            if (ei >= cnt) w = 0.f;
            S += w;
            uint4 d = *(const uint4*)(f + (size_t)s * 256 + c8);
            acc[0] = fmaf(w, blo(d.x), acc[0]); acc[1] = fmaf(w, bhi(d.x), acc[1]);
            acc[2] = fmaf(w, blo(d.y), acc[2]); acc[3] = fmaf(w, bhi(d.y), acc[3]);
            acc[4] = fmaf(w, blo(d.z), acc[4]); acc[5] = fmaf(w, bhi(d.z), acc[5]);
            acc[6] = fmaf(w, blo(d.w), acc[6]); acc[7] = fmaf(w, bhi(d.w), acc[7]);
        }
    }
    #pragma unroll
    for (int k = 0; k < 8; k++) acc[k] += __shfl_xor(acc[k], 32);
    S += __shfl_xor(S, 32);
    if (half == 0) {
        float inv = 1.f / (S + 1e-16f);
        float4 b0 = *(const float4*)(bias + c8);
        float4 b1 = *(const float4*)(bias + c8 + 4);
        float v[8];
        v[0] = acc[0] * inv + b0.x; v[1] = acc[1] * inv + b0.y;
        v[2] = acc[2] * inv + b0.z; v[3] = acc[3] * inv + b0.w;
        v[4] = acc[4] * inv + b1.x; v[5] = acc[5] * inv + b1.y;
        v[6] = acc[6] * inv + b1.z; v[7] = acc[7] * inv + b1.w;
        if (resb) {
            uint4 r = *(const uint4*)(resb + (size_t)i * 256 + c8);
            v[0] += blo(r.x); v[1] += bhi(r.x); v[2] += blo(r.y); v[3] += bhi(r.y);
            v[4] += blo(r.z); v[5] += bhi(r.z); v[6] += blo(r.w); v[7] += bhi(r.w);
        }
        #pragma unroll
        for (int k = 0; k < 8; k++) v[k] = v[k] > 0.f ? v[k] : (__expf(v[k]) - 1.f);  // ELU
        uint4 o;
        o.x = (unsigned)f2b(v[0]) | ((unsigned)f2b(v[1]) << 16);
        o.y = (unsigned)f2b(v[2]) | ((unsigned)f2b(v[3]) << 16);
        o.z = (unsigned)f2b(v[4]) | ((unsigned)f2b(v[5]) << 16);
        o.w = (unsigned)f2b(v[6]) | ((unsigned)f2b(v[7]) << 16);
        *(uint4*)(outb + (size_t)i * 256 + c8) = o;
    }
}

// ---------------- fused softmax+agg, layer 3 (6 heads): WAVE per node, uint4 ----------------
// S[li, h*256+c] = (1/(6*Sum_h)) * sum_j ex_jh * x[src_j, c]

__global__ __launch_bounds__(256) void aggS_fused(
    const u16* __restrict__ x, const float* __restrict__ al3,
    const int* __restrict__ row_ptr, const int* __restrict__ csr_src,
    u16* __restrict__ S, int node0, int count) {
    __shared__ int s_i[4][16];
    __shared__ float s_w[4][96];
    int wid = threadIdx.x >> 6, lane = threadIdx.x & 63;
    int li = blockIdx.x * 4 + wid;
    if (li >= count) return;
    int i = node0 + li;
    int beg = row_ptr[i], end = row_ptr[i + 1];
    int half = lane >> 5;
    int c8 = (lane & 31) * 8;
    int e16 = lane & 15;
    int hA = lane >> 4;            // heads 0-3 staging
    int hB = 4 + (lane >> 4);      // heads 4-5 staging (lanes 0-31)
    float aldA = al3[(size_t)i * 12 + 6 + hA];
    float aldB = (lane < 32) ? al3[(size_t)i * 12 + 6 + hB] : 0.f;
    float acc[6][8] = {};
    float Ssum[6] = {};
    for (int base = beg; base < end; base += 16) {
        int cnt = min(16, end - base);
        int idxe = csr_src[base + min(e16, cnt - 1)];
        if (lane < 16) s_i[wid][lane] = idxe;
        float vA = al3[(size_t)idxe * 12 + hA] + aldA;
        vA = vA > 0.f ? vA : 0.2f * vA;
        float exA = __expf(fminf(vA, 60.f));
        if (e16 < cnt) s_w[wid][e16 * 6 + hA] = exA;
        if (lane < 32) {
            float vB = al3[(size_t)idxe * 12 + hB] + aldB;
            vB = vB > 0.f ? vB : 0.2f * vB;
            float exB = __expf(fminf(vB, 60.f));
            if (e16 < cnt) s_w[wid][e16 * 6 + hB] = exB;
        }
        // wave-coherent LDS (lockstep), no barrier
        for (int e = 0; e < cnt; e += 2) {
            int ei = e + half;
            bool valid = ei < cnt;
            int eu = valid ? ei : e;
            int s = s_i[wid][eu];
            uint4 d = *(const uint4*)(x + (size_t)s * 256 + c8);
            float v0 = blo(d.x), v1 = bhi(d.x), v2 = blo(d.y), v3 = bhi(d.y);
            float v4 = blo(d.z), v5 = bhi(d.z), v6 = blo(d.w), v7 = bhi(d.w);
            #pragma unroll
            for (int hh = 0; hh < 6; hh++) {
                float w = valid ? s_w[wid][eu * 6 + hh] : 0.f;
                Ssum[hh] += w;
                acc[hh][0] = fmaf(w, v0, acc[hh][0]);
                acc[hh][1] = fmaf(w, v1, acc[hh][1]);
                acc[hh][2] = fmaf(w, v2, acc[hh][2]);
                acc[hh][3] = fmaf(w, v3, acc[hh][3]);
                acc[hh][4] = fmaf(w, v4, acc[hh][4]);
                acc[hh][5] = fmaf(w, v5, acc[hh][5]);
                acc[hh][6] = fmaf(w, v6, acc[hh][6]);
                acc[hh][7] = fmaf(w, v7, acc[hh][7]);
            }
        }
    }
    #pragma unroll
    for (int hh = 0; hh < 6; hh++) {
        Ssum[hh] += __shfl_xor(Ssum[hh], 32);
        #pragma unroll
        for (int k = 0; k < 8; k++) acc[hh][k] += __shfl_xor(acc[hh][k], 32);
    }
    if (half == 0) {
        #pragma unroll
        for (int hh = 0; hh < 6; hh++) {
            float inv = 1.f / (6.f * (Ssum[hh] + 1e-16f));
            uint4 o;
            o.x = (unsigned)f2b(acc[hh][0] * inv) | ((unsigned)f2b(acc[hh][1] * inv) << 16);
            o.y = (unsigned)f2b(acc[hh][2] * inv) | ((unsigned)f2b(acc[hh][3] * inv) << 16);
            o.z = (unsigned)f2b(acc[hh][4] * inv) | ((unsigned)f2b(acc[hh][5] * inv) << 16);
            o.w = (unsigned)f2b(acc[hh][6] * inv) | ((unsigned)f2b(acc[hh][7] * inv) << 16);
            *(uint4*)(S + (size_t)li * 1536 + hh * 256 + c8) = o;
        }
    }
}

// ---------------- host ----------------

extern "C" void kernel_launch(void* const* d_in, const int* in_sizes, int n_in,
                              void* d_out, int out_size, void* d_ws, size_t ws_size,
                              hipStream_t stream) {
    const float* x      = (const float*)d_in[0];
    const int*   src    = (const int*)d_in[1];
    const int*   dst    = (const int*)d_in[2];
    const float* W1     = (const float*)d_in[3];
    const float* a1_src = (const float*)d_in[4];
    const float* a1_dst = (const float*)d_in[5];
    const float* b1     = (const float*)d_in[6];
    const float* W2     = (const float*)d_in[7];
    const float* a2_src = (const float*)d_in[8];
    const float* a2_dst = (const float*)d_in[9];
    const float* b2     = (const float*)d_in[10];
    const float* Wres2  = (const float*)d_in[11];
    const float* W3     = (const float*)d_in[12];
    const float* a3_src = (const float*)d_in[13];
    const float* a3_dst = (const float*)d_in[14];
    const float* b3     = (const float*)d_in[15];
    float* out = (float*)d_out;

    const int N = NODES, E = EDGES;
    const int EN = E + N;
    const int NB = (N + 255) / 256;  // 196

    char* p = (char*)d_ws;
    auto alloc = [&](size_t bytes) -> char* {
        char* r = p;
        p += (bytes + 511) & ~(size_t)511;
        return r;
    };
    // persistent
    int*   row_ptr = (int*)alloc((size_t)(N + 1) * sizeof(int));
    int*   cursor  = (int*)alloc((size_t)N * sizeof(int));
    int*   deg     = (int*)alloc((size_t)N * sizeof(int));
    int*   bsum    = (int*)alloc(256 * sizeof(int));
    int*   csr_src = (int*)alloc((size_t)EN * sizeof(int));
    float* al      = (float*)alloc((size_t)N * 12 * sizeof(float));
    float* cm      = (float*)alloc((size_t)12 * 256 * sizeof(float));
    u16*   o2b     = (u16*)alloc((size_t)MPAD * 256 * sizeof(u16));
    u16*   WT2     = (u16*)alloc((size_t)512 * 256 * sizeof(u16));
    u16*   W3sT    = (u16*)alloc((size_t)128 * 1536 * sizeof(u16));
    // region2 (phase-overlaid)
    const size_t A2B_B  = (size_t)MPAD * 256 * sizeof(u16);
    const size_t F1B_B  = (size_t)N * 256 * sizeof(u16);
    const size_t RESB_B = (size_t)N * 256 * sizeof(u16);
    const size_t S_B    = (size_t)C0 * 1536 * sizeof(u16);
    size_t r2_bytes = A2B_B + F1B_B + RESB_B;
    if (S_B > r2_bytes) r2_bytes = S_B;
    char* r2 = alloc(r2_bytes + 1024);
    u16* A2b  = (u16*)r2;                        // layer-1 out bf16 [MPAD,256]
    u16* f1b  = (u16*)(r2 + A2B_B);              // layer feat bf16 [N,256]
    u16* resb = (u16*)(r2 + A2B_B + F1B_B);      // layer-2 residual bf16 [N,256]
    u16* A2a  = (u16*)(r2 + A2B_B + F1B_B);      // x bf16 [MPAD,128] (dead before resb)
    u16* Sb   = (u16*)r2;                        // S chunk bf16 [C0,1536] (layer 3)
    (void)ws_size; (void)n_in; (void)in_sizes; (void)out_size;

    float* al_s = al;
    float* al_d = al + (size_t)4 * N;

    // --- CSR build ---
    fill_ones_kernel<<<NB, 256, 0, stream>>>(deg, N);
    hist_kernel<<<(E + 255) / 256, 256, 0, stream>>>(dst, deg, E);
    deg_bsum_kernel<<<NB, 256, 0, stream>>>(deg, bsum, N);
    bsum_scan_kernel<<<1, 256, 0, stream>>>(bsum, row_ptr, NB, N);
    deg_scan_kernel<<<NB, 256, 0, stream>>>(deg, bsum, row_ptr, cursor, N);
    scatter_kernel<<<(E + N + 255) / 256, 256, 0, stream>>>(src, dst, E, N, cursor, csr_src);

    int nwb = (N + 3) / 4;

    // --- layer 1: 128 -> 4x64 concat, ELU ---
    convertA4_kernel<<<(N * 128 / 4 + 255) / 256, 256, 0, stream>>>(x, A2a, N * 128 / 4);
    convertW_kernel<<<(256 * 128 + 255) / 256, 256, 0, stream>>>(W1, 256, 0, 256, 256, 128, WT2);
    {
        dim3 g(MPAD / 128, 2);
        gemm_mfma_kernel<<<g, 256, 0, stream>>>(A2a, WT2, f1b, nullptr, N, 256, 128, 256, 9999);
    }
    row_alpha4_kernel<<<nwb, 256, 0, stream>>>(f1b, a1_src, a1_dst, al_s, al_d, N);
    agg4_fused<<<nwb, 256, 0, stream>>>(f1b, al_s, al_d, row_ptr, csr_src, b1, nullptr, A2b, N);

    // --- layer 2: 256 -> 4x64 concat + residual (one 512-wide GEMM), ELU ---
    convertW_kernel<<<(256 * 256 + 255) / 256, 256, 0, stream>>>(W2, 256, 0, 256, 256, 256, WT2);
    convertW_kernel<<<(256 * 256 + 255) / 256, 256, 0, stream>>>(Wres2, 256, 0, 256, 256, 256,
                                                                 WT2 + (size_t)256 * 256);
    {
        dim3 g(MPAD / 128, 4);
        gemm_mfma_kernel<<<g, 256, 0, stream>>>(A2b, WT2, f1b, resb, N, 512, 256, 256, 256);
    }
    row_alpha4_kernel<<<nwb, 256, 0, stream>>>(f1b, a2_src, a2_dst, al_s, al_d, N);
    agg4_fused<<<nwb, 256, 0, stream>>>(f1b, al_s, al_d, row_ptr, csr_src, b2, resb, o2b, N);

    // --- layer 3: logits -> fused softmax+input-space agg -> skinny GEMM ---
    prep_cmat_kernel<<<(12 * 256 + 255) / 256, 256, 0, stream>>>(W3, a3_src, a3_dst, cm);
    al3_kernel<<<nwb, 256, 0, stream>>>(o2b, cm, al, N);
    convertW3stack_kernel<<<(128 * 1536 + 255) / 256, 256, 0, stream>>>(W3, W3sT);
    {
        aggS_fused<<<(C0 + 3) / 4, 256, 0, stream>>>(o2b, al, row_ptr, csr_src, Sb, 0, C0);
        gemm_skinny<<<(C0 + 31) / 32, 256, 0, stream>>>(Sb, W3sT, out, b3, C0);
        aggS_fused<<<(C1 + 3) / 4, 256, 0, stream>>>(o2b, al, row_ptr, csr_src, Sb, C0, C1);
        gemm_skinny<<<(C1 + 31) / 32, 256, 0, stream>>>(Sb, W3sT, out + (size_t)C0 * 121, b3, C1);
    }
}

// Round 7
// 693.226 us; speedup vs baseline: 1.0120x; 1.0120x over previous
//
#include <hip/hip_runtime.h>
#include <hip/hip_bf16.h>

// PPI GAT, 3 layers. N=50000, E=800000 (+N self loops), avg degree ~17.
// R7: revert aggS to R5 form (R6 regression), coalesced 64-row skinny GEMM,
//     logits fused into producers via (x@W)·a = x·(W@a) precomputed q-vectors,
//     single prep_weights kernel. 16 launches.

#define NODES 50000
#define EDGES 800000
#define MPAD  50048            // ceil(N/128)*128
#define C0    25088            // layer-3 chunk-0 rows
#define C1    24912            // layer-3 chunk-1 rows

typedef unsigned short u16;
typedef __attribute__((ext_vector_type(8))) short bf16x8;
typedef __attribute__((ext_vector_type(4))) float f32x4;

__device__ __forceinline__ float bf16f(u16 r) {
    return __uint_as_float(((unsigned)r) << 16);
}
__device__ __forceinline__ u16 f2b(float v) {
    __hip_bfloat16 b = __float2bfloat16(v);
    return *(u16*)&b;
}
__device__ __forceinline__ float blo(unsigned d) { return __uint_as_float(d << 16); }
__device__ __forceinline__ float bhi(unsigned d) { return __uint_as_float(d & 0xffff0000u); }

// ---------------- CSR build ----------------

__global__ void fill_ones_kernel(int* __restrict__ deg, int n) {
    int i = blockIdx.x * blockDim.x + threadIdx.x;
    if (i < n) deg[i] = 1;  // self-loop
}

__global__ void hist_kernel(const int* __restrict__ dst, int* __restrict__ deg, int E) {
    int e = blockIdx.x * blockDim.x + threadIdx.x;
    if (e < E) atomicAdd(&deg[dst[e]], 1);
}

__global__ void deg_bsum_kernel(const int* __restrict__ deg, int* __restrict__ bsum, int n) {
    int tid = threadIdx.x, lane = tid & 63, wid = tid >> 6;
    int i = blockIdx.x * 256 + tid;
    int v = (i < n) ? deg[i] : 0;
    #pragma unroll
    for (int ofs = 32; ofs > 0; ofs >>= 1) v += __shfl_down(v, ofs);
    __shared__ int sp[4];
    if (lane == 0) sp[wid] = v;
    __syncthreads();
    if (tid == 0) bsum[blockIdx.x] = sp[0] + sp[1] + sp[2] + sp[3];
}

__global__ void bsum_scan_kernel(int* __restrict__ bsum, int* __restrict__ row_ptr,
                                 int nb, int n) {
    int tid = threadIdx.x, lane = tid & 63, wid = tid >> 6;
    int v = (tid < nb) ? bsum[tid] : 0;
    int incl = v;
    #pragma unroll
    for (int ofs = 1; ofs < 64; ofs <<= 1) {
        int t = __shfl_up(incl, ofs);
        if (lane >= ofs) incl += t;
    }
    __shared__ int sp[4];
    if (lane == 63) sp[wid] = incl;
    __syncthreads();
    int add = 0;
    for (int k = 0; k < wid; k++) add += sp[k];
    int excl = incl - v + add;
    if (tid < nb) bsum[tid] = excl;
    if (tid == nb - 1) row_ptr[n] = excl + v;
}

__global__ void deg_scan_kernel(const int* __restrict__ deg, const int* __restrict__ bofs,
                                int* __restrict__ row_ptr, int* __restrict__ cursor, int n) {
    int tid = threadIdx.x, lane = tid & 63, wid = tid >> 6;
    int i = blockIdx.x * 256 + tid;
    int v = (i < n) ? deg[i] : 0;
    int incl = v;
    #pragma unroll
    for (int ofs = 1; ofs < 64; ofs <<= 1) {
        int t = __shfl_up(incl, ofs);
        if (lane >= ofs) incl += t;
    }
    __shared__ int sp[4];
    if (lane == 63) sp[wid] = incl;
    __syncthreads();
    int add = bofs[blockIdx.x];
    for (int k = 0; k < wid; k++) add += sp[k];
    int excl = incl - v + add;
    if (i < n) { row_ptr[i] = excl; cursor[i] = excl; }
}

__global__ void scatter_kernel(const int* __restrict__ src, const int* __restrict__ dst,
                               int E, int n, int* __restrict__ cursor, int* __restrict__ csr_src) {
    int e = blockIdx.x * blockDim.x + threadIdx.x;
    if (e < E) {
        int d = dst[e];
        int p = atomicAdd(&cursor[d], 1);
        csr_src[p] = src[e];
    } else if (e < E + n) {
        int i = e - E;
        int p = atomicAdd(&cursor[i], 1);
        csr_src[p] = i;  // self-loop
    }
}

// ---------------- prep: all weight converts + q-vectors, one launch ----------------
// WT1[256][128] = W1^T; WT2[512][256] = [W2|Wres2]^T; W3sT[128][1536] stacked-head W3^T.
// q1t[8][128] = W1 @ a1 (rows 0-3 src, 4-7 dst); q2t[8][256] = W2 @ a2; cm[12][256] = W3h @ a3.

__global__ void prep_weights(
    const float* __restrict__ W1, const float* __restrict__ W2,
    const float* __restrict__ Wres2, const float* __restrict__ W3,
    const float* __restrict__ a1s, const float* __restrict__ a1d,
    const float* __restrict__ a2s, const float* __restrict__ a2d,
    const float* __restrict__ a3s, const float* __restrict__ a3d,
    u16* __restrict__ WT1, u16* __restrict__ WT2, u16* __restrict__ W3sT,
    float* __restrict__ q1t, float* __restrict__ q2t, float* __restrict__ cm) {
    int idx = blockIdx.x * 256 + threadIdx.x;
    if (idx < 32768) {                        // WT1
        int n = idx >> 7, k = idx & 127;
        WT1[idx] = f2b(W1[(size_t)k * 256 + n]);
    } else if ((idx -= 32768) < 131072) {     // WT2 = [W2 | Wres2]
        int n = idx >> 8, k = idx & 255;
        float v = (n < 256) ? W2[(size_t)k * 256 + n] : Wres2[(size_t)k * 256 + (n - 256)];
        WT2[idx] = f2b(v);
    } else if ((idx -= 131072) < 196608) {    // W3sT
        int n = idx / 1536, q = idx % 1536;
        int h = q >> 8, k = q & 255;
        W3sT[idx] = f2b((n < 121) ? W3[(size_t)k * 726 + h * 121 + n] : 0.f);
    } else if ((idx -= 196608) < 1024) {      // q1t
        int h = idx >> 7, k = idx & 127;
        int hh = h & 3;
        const float* a = (h < 4) ? a1s : a1d;
        float v = 0.f;
        for (int c = 0; c < 64; c++) v += W1[(size_t)k * 256 + hh * 64 + c] * a[hh * 64 + c];
        q1t[idx] = v;
    } else if ((idx -= 1024) < 2048) {        // q2t
        int h = idx >> 8, k = idx & 255;
        int hh = h & 3;
        const float* a = (h < 4) ? a2s : a2d;
        float v = 0.f;
        for (int c = 0; c < 64; c++) v += W2[(size_t)k * 256 + hh * 64 + c] * a[hh * 64 + c];
        q2t[idx] = v;
    } else if ((idx -= 2048) < 3072) {        // cm
        int o = idx >> 8, k = idx & 255;
        int h = (o < 6) ? o : o - 6;
        const float* a = (o < 6) ? a3s : a3d;
        float v = 0.f;
        for (int c = 0; c < 121; c++) v += W3[(size_t)k * 726 + h * 121 + c] * a[h * 121 + c];
        cm[idx] = v;
    }
}
#define PREP_TOTAL (32768 + 131072 + 196608 + 1024 + 2048 + 3072)

// ---------------- convx + layer-1 logits: wave per node ----------------
// A2a[i] = bf16(x[i]); alA[i][h] = x_i . q1t[h]  (h<4 src, h>=4 dst)

__global__ __launch_bounds__(256) void convx_al1(
    const float* __restrict__ x, const float* __restrict__ q1t,
    u16* __restrict__ A2a, float* __restrict__ alA, int n) {
    int wid = threadIdx.x >> 6, lane = threadIdx.x & 63;
    int i = blockIdx.x * 4 + wid;
    if (i >= n) return;
    float2 xv = *(const float2*)(x + (size_t)i * 128 + lane * 2);
    ushort2 o;
    o.x = f2b(xv.x); o.y = f2b(xv.y);
    *(ushort2*)(A2a + (size_t)i * 128 + lane * 2) = o;
    float p[8];
    #pragma unroll
    for (int h = 0; h < 8; h++) {
        float2 q = *(const float2*)(q1t + h * 128 + lane * 2);
        p[h] = xv.x * q.x + xv.y * q.y;
    }
    #pragma unroll
    for (int ofs = 1; ofs <= 32; ofs <<= 1) {
        #pragma unroll
        for (int h = 0; h < 8; h++) p[h] += __shfl_xor(p[h], ofs);
    }
    if (lane == 0) {
        *(float4*)(alA + (size_t)i * 8)     = make_float4(p[0], p[1], p[2], p[3]);
        *(float4*)(alA + (size_t)i * 8 + 4) = make_float4(p[4], p[5], p[6], p[7]);
    }
}

// ---------------- bf16 MFMA GEMM (square-ish): C = A @ B^T, bf16 out, col split ----------------

__global__ __launch_bounds__(256) void gemm_mfma_kernel(
    const u16* __restrict__ A, const u16* __restrict__ B,
    u16* __restrict__ Cb, u16* __restrict__ Cb2,
    int M, int Ncols, int K2, int ldc, int split) {
    __shared__ __align__(16) u16 As[128][40];
    __shared__ __align__(16) u16 Bs[128][40];
    int tid = threadIdx.x;
    int lane = tid & 63;
    int wv = tid >> 6;
    int quad = lane >> 4, lm = lane & 15;
    int wm = (wv & 1) * 64, wn = (wv >> 1) * 64;
    int bm = blockIdx.x * 128, bn = blockIdx.y * 128;

    f32x4 zero = {0.f, 0.f, 0.f, 0.f};
    f32x4 acc[4][4];
    #pragma unroll
    for (int i = 0; i < 4; i++)
        #pragma unroll
        for (int j = 0; j < 4; j++) acc[i][j] = zero;

    for (int k0 = 0; k0 < K2; k0 += 32) {
        #pragma unroll
        for (int it = 0; it < 2; ++it) {
            int chunk = tid + it * 256;
            int row = chunk >> 2, seg = chunk & 3;
            uint4 va = *(const uint4*)(A + (size_t)(bm + row) * K2 + k0 + seg * 8);
            uint4 vb = *(const uint4*)(B + (size_t)(bn + row) * K2 + k0 + seg * 8);
            *(uint4*)&As[row][seg * 8] = va;
            *(uint4*)&Bs[row][seg * 8] = vb;
        }
        __syncthreads();
        bf16x8 af[4], bfr[4];
        #pragma unroll
        for (int i = 0; i < 4; i++) af[i] = *(const bf16x8*)&As[wm + i * 16 + lm][quad * 8];
        #pragma unroll
        for (int j = 0; j < 4; j++) bfr[j] = *(const bf16x8*)&Bs[wn + j * 16 + lm][quad * 8];
        #pragma unroll
        for (int i = 0; i < 4; i++)
            #pragma unroll
            for (int j = 0; j < 4; j++)
                acc[i][j] = __builtin_amdgcn_mfma_f32_16x16x32_bf16(af[i], bfr[j], acc[i][j], 0, 0, 0);
        __syncthreads();
    }

    // C/D layout: col = lane&15, row = quad*4 + reg
    #pragma unroll
    for (int i = 0; i < 4; i++) {
        #pragma unroll
        for (int j = 0; j < 4; j++) {
            int col = bn + wn + j * 16 + lm;
            if (col >= Ncols) continue;
            int row_base = bm + wm + i * 16 + quad * 4;
            #pragma unroll
            for (int r = 0; r < 4; r++) {
                int row = row_base + r;
                if (row >= M) continue;
                float v = acc[i][j][r];
                if (col < split) Cb[(size_t)row * ldc + col] = f2b(v);
                else             Cb2[(size_t)row * ldc + col - split] = f2b(v);
            }
        }
    }
}

// ---------------- skinny GEMM (layer 3): C[count,121] = A[count,1536] @ B[128,1536]^T ----
// 64-row x 128-col block tile; A and B staged via coalesced LDS loads.
// wave wv: rows (wv>>1)*32, cols (wv&1)*64; 8 MFMA/iter. sigmoid(v+bias) epilogue.

__global__ __launch_bounds__(256) void gemm_skinny64(
    const u16* __restrict__ A, const u16* __restrict__ B,
    float* __restrict__ C, const float* __restrict__ bias, int count) {
    __shared__ __align__(16) u16 As[64][40];
    __shared__ __align__(16) u16 Bs[128][40];
    int tid = threadIdx.x, lane = tid & 63, wv = tid >> 6;
    int quad = lane >> 4, lm = lane & 15;
    int bm = blockIdx.x * 64;
    int mrow = (wv >> 1) * 32, ncol = (wv & 1) * 64;
    int ar = bm + (tid >> 2);
    if (ar >= count) ar = count - 1;
    const u16* Ap = A + (size_t)ar * 1536 + (tid & 3) * 8;

    f32x4 zero = {0.f, 0.f, 0.f, 0.f};
    f32x4 acc[2][4];
    #pragma unroll
    for (int i = 0; i < 2; i++)
        #pragma unroll
        for (int j = 0; j < 4; j++) acc[i][j] = zero;

    for (int k0 = 0; k0 < 1536; k0 += 32) {
        *(uint4*)&As[tid >> 2][(tid & 3) * 8] = *(const uint4*)(Ap + k0);
        #pragma unroll
        for (int it = 0; it < 2; ++it) {
            int t = tid + it * 256;
            *(uint4*)&Bs[t >> 2][(t & 3) * 8] =
                *(const uint4*)(B + (size_t)(t >> 2) * 1536 + k0 + (t & 3) * 8);
        }
        __syncthreads();
        bf16x8 af[2], bfr[4];
        #pragma unroll
        for (int i = 0; i < 2; i++) af[i] = *(const bf16x8*)&As[mrow + i * 16 + lm][quad * 8];
        #pragma unroll
        for (int j = 0; j < 4; j++) bfr[j] = *(const bf16x8*)&Bs[ncol + j * 16 + lm][quad * 8];
        #pragma unroll
        for (int i = 0; i < 2; i++)
            #pragma unroll
            for (int j = 0; j < 4; j++)
                acc[i][j] = __builtin_amdgcn_mfma_f32_16x16x32_bf16(af[i], bfr[j], acc[i][j], 0, 0, 0);
        __syncthreads();
    }

    #pragma unroll
    for (int i = 0; i < 2; i++) {
        #pragma unroll
        for (int j = 0; j < 4; j++) {
            int col = ncol + j * 16 + lm;
            if (col >= 121) continue;
            int row_base = bm + mrow + i * 16 + quad * 4;
            #pragma unroll
            for (int r = 0; r < 4; r++) {
                int row = row_base + r;
                if (row >= count) continue;
                float v = acc[i][j][r] + bias[col];
                v = 1.f / (1.f + __expf(-v));
                C[(size_t)row * 121 + col] = v;
            }
        }
    }
}

// ---------------- fused softmax+agg, layers 1&2: WAVE per node ----------------
// al8 layout: [i][0..3]=src logits, [i][4..7]=dst logits.
// Epilogue: ELU output row (lanes 0-31 x 8ch) -> optional next-layer logits via q8/q12.

__global__ __launch_bounds__(256) void agg4_fused(
    const u16* __restrict__ f, const float* __restrict__ al8,
    const int* __restrict__ row_ptr, const int* __restrict__ csr_src,
    const float* __restrict__ bias, const u16* __restrict__ resb,
    u16* __restrict__ outb,
    const float* __restrict__ q8, float* __restrict__ alB,
    const float* __restrict__ q12, float* __restrict__ al12, int n) {
    int wid = threadIdx.x >> 6, lane = threadIdx.x & 63;
    int i = blockIdx.x * 4 + wid;
    if (i >= n) return;
    int beg = row_ptr[i], end = row_ptr[i + 1];
    int h_st = lane >> 4;        // staging head
    int el = lane & 15;          // staging edge slot
    int half = lane >> 5;        // edge parity
    int c8 = (lane & 31) * 8;    // this lane's 8 channels
    float ald_st = al8[(size_t)i * 8 + 4 + h_st];
    float acc[8] = {};
    float S = 0.f;
    for (int base = beg; base < end; base += 16) {
        int cnt = min(16, end - base);
        int idxv = csr_src[base + min(el, cnt - 1)];
        float av = al8[(size_t)idxv * 8 + h_st] + ald_st;
        av = av > 0.f ? av : 0.2f * av;
        float ex = __expf(fminf(av, 60.f));
        for (int e = 0; e < cnt; e += 2) {
            int ei = e + half;
            int eu = ei < cnt ? ei : e;
            int s = __shfl(idxv, eu);
            float w = __shfl(ex, ((lane & 24) << 1) | eu);
            if (ei >= cnt) w = 0.f;
            S += w;
            uint4 d = *(const uint4*)(f + (size_t)s * 256 + c8);
            acc[0] = fmaf(w, blo(d.x), acc[0]); acc[1] = fmaf(w, bhi(d.x), acc[1]);
            acc[2] = fmaf(w, blo(d.y), acc[2]); acc[3] = fmaf(w, bhi(d.y), acc[3]);
            acc[4] = fmaf(w, blo(d.z), acc[4]); acc[5] = fmaf(w, bhi(d.z), acc[5]);
            acc[6] = fmaf(w, blo(d.w), acc[6]); acc[7] = fmaf(w, bhi(d.w), acc[7]);
        }
    }
    #pragma unroll
    for (int k = 0; k < 8; k++) acc[k] += __shfl_xor(acc[k], 32);
    S += __shfl_xor(S, 32);
    if (half == 0) {
        float inv = 1.f / (S + 1e-16f);
        float4 b0 = *(const float4*)(bias + c8);
        float4 b1 = *(const float4*)(bias + c8 + 4);
        float v[8];
        v[0] = acc[0] * inv + b0.x; v[1] = acc[1] * inv + b0.y;
        v[2] = acc[2] * inv + b0.z; v[3] = acc[3] * inv + b0.w;
        v[4] = acc[4] * inv + b1.x; v[5] = acc[5] * inv + b1.y;
        v[6] = acc[6] * inv + b1.z; v[7] = acc[7] * inv + b1.w;
        if (resb) {
            uint4 r = *(const uint4*)(resb + (size_t)i * 256 + c8);
            v[0] += blo(r.x); v[1] += bhi(r.x); v[2] += blo(r.y); v[3] += bhi(r.y);
            v[4] += blo(r.z); v[5] += bhi(r.z); v[6] += blo(r.w); v[7] += bhi(r.w);
        }
        #pragma unroll
        for (int k = 0; k < 8; k++) v[k] = v[k] > 0.f ? v[k] : (__expf(v[k]) - 1.f);  // ELU
        uint4 o;
        o.x = (unsigned)f2b(v[0]) | ((unsigned)f2b(v[1]) << 16);
        o.y = (unsigned)f2b(v[2]) | ((unsigned)f2b(v[3]) << 16);
        o.z = (unsigned)f2b(v[4]) | ((unsigned)f2b(v[5]) << 16);
        o.w = (unsigned)f2b(v[6]) | ((unsigned)f2b(v[7]) << 16);
        *(uint4*)(outb + (size_t)i * 256 + c8) = o;
        // next-layer logits from the in-register output row (32 lanes x 8 ch)
        if (alB) {
            float pj[8];
            #pragma unroll
            for (int h = 0; h < 8; h++) {
                const float* qp = q8 + h * 256 + c8;
                float4 qa = *(const float4*)qp;
                float4 qb = *(const float4*)(qp + 4);
                pj[h] = v[0] * qa.x + v[1] * qa.y + v[2] * qa.z + v[3] * qa.w
                      + v[4] * qb.x + v[5] * qb.y + v[6] * qb.z + v[7] * qb.w;
            }
            #pragma unroll
            for (int ofs = 1; ofs <= 16; ofs <<= 1) {
                #pragma unroll
                for (int h = 0; h < 8; h++) pj[h] += __shfl_xor(pj[h], ofs);
            }
            if (lane == 0) {
                *(float4*)(alB + (size_t)i * 8)     = make_float4(pj[0], pj[1], pj[2], pj[3]);
                *(float4*)(alB + (size_t)i * 8 + 4) = make_float4(pj[4], pj[5], pj[6], pj[7]);
            }
        }
        if (al12) {
            float pj[12];
            #pragma unroll
            for (int o12 = 0; o12 < 12; o12++) {
                const float* qp = q12 + o12 * 256 + c8;
                float4 qa = *(const float4*)qp;
                float4 qb = *(const float4*)(qp + 4);
                pj[o12] = v[0] * qa.x + v[1] * qa.y + v[2] * qa.z + v[3] * qa.w
                        + v[4] * qb.x + v[5] * qb.y + v[6] * qb.z + v[7] * qb.w;
            }
            #pragma unroll
            for (int ofs = 1; ofs <= 16; ofs <<= 1) {
                #pragma unroll
                for (int o12 = 0; o12 < 12; o12++) pj[o12] += __shfl_xor(pj[o12], ofs);
            }
            if (lane == 0) {
                *(float4*)(al12 + (size_t)i * 12)     = make_float4(pj[0], pj[1], pj[2], pj[3]);
                *(float4*)(al12 + (size_t)i * 12 + 4) = make_float4(pj[4], pj[5], pj[6], pj[7]);
                *(float4*)(al12 + (size_t)i * 12 + 8) = make_float4(pj[8], pj[9], pj[10], pj[11]);
            }
        }
    }
}

// ---------------- fused softmax+agg, layer 3 (6 heads): WAVE per node (R5 form) ----------------

__global__ __launch_bounds__(256) void aggS_fused(
    const u16* __restrict__ x, const float* __restrict__ al3,
    const int* __restrict__ row_ptr, const int* __restrict__ csr_src,
    u16* __restrict__ S, int node0, int count) {
    __shared__ int s_i[4][16];
    __shared__ float s_w[4][96];
    int wid = threadIdx.x >> 6, lane = threadIdx.x & 63;
    int li = blockIdx.x * 4 + wid;
    if (li >= count) return;
    int i = node0 + li;
    int beg = row_ptr[i], end = row_ptr[i + 1];
    int c4 = lane * 4;
    int e16 = lane & 15;
    int hA = lane >> 4;            // heads 0-3 staging
    int hB = 4 + (lane >> 4);      // heads 4-5 staging (lanes 0-31)
    float aldA = al3[(size_t)i * 12 + 6 + hA];
    float aldB = (lane < 32) ? al3[(size_t)i * 12 + 6 + hB] : 0.f;
    float acc[6][4] = {};
    float Ssum[6] = {};
    for (int base = beg; base < end; base += 16) {
        int cnt = min(16, end - base);
        int idxe = csr_src[base + min(e16, cnt - 1)];
        if (lane < 16) s_i[wid][lane] = idxe;
        float vA = al3[(size_t)idxe * 12 + hA] + aldA;
        vA = vA > 0.f ? vA : 0.2f * vA;
        float exA = __expf(fminf(vA, 60.f));
        if (e16 < cnt) s_w[wid][e16 * 6 + hA] = exA;
        if (lane < 32) {
            float vB = al3[(size_t)idxe * 12 + hB] + aldB;
            vB = vB > 0.f ? vB : 0.2f * vB;
            float exB = __expf(fminf(vB, 60.f));
            if (e16 < cnt) s_w[wid][e16 * 6 + hB] = exB;
        }
        // wave-coherent LDS (lockstep), no barrier
        for (int e = 0; e < cnt; e++) {
            int s = s_i[wid][e];
            uint2 d = *(const uint2*)(x + (size_t)s * 256 + c4);
            float v0 = blo(d.x), v1 = bhi(d.x), v2 = blo(d.y), v3 = bhi(d.y);
            #pragma unroll
            for (int hh = 0; hh < 6; hh++) {
                float w = s_w[wid][e * 6 + hh];
                Ssum[hh] += w;
                acc[hh][0] = fmaf(w, v0, acc[hh][0]);
                acc[hh][1] = fmaf(w, v1, acc[hh][1]);
                acc[hh][2] = fmaf(w, v2, acc[hh][2]);
                acc[hh][3] = fmaf(w, v3, acc[hh][3]);
            }
        }
    }
    #pragma unroll
    for (int hh = 0; hh < 6; hh++) {
        float inv = 1.f / (6.f * (Ssum[hh] + 1e-16f));
        ushort4 o;
        o.x = f2b(acc[hh][0] * inv);
        o.y = f2b(acc[hh][1] * inv);
        o.z = f2b(acc[hh][2] * inv);
        o.w = f2b(acc[hh][3] * inv);
        *(ushort4*)(S + (size_t)li * 1536 + hh * 256 + c4) = o;
    }
}

// ---------------- host ----------------

extern "C" void kernel_launch(void* const* d_in, const int* in_sizes, int n_in,
                              void* d_out, int out_size, void* d_ws, size_t ws_size,
                              hipStream_t stream) {
    const float* x      = (const float*)d_in[0];
    const int*   src    = (const int*)d_in[1];
    const int*   dst    = (const int*)d_in[2];
    const float* W1     = (const float*)d_in[3];
    const float* a1_src = (const float*)d_in[4];
    const float* a1_dst = (const float*)d_in[5];
    const float* b1     = (const float*)d_in[6];
    const float* W2     = (const float*)d_in[7];
    const float* a2_src = (const float*)d_in[8];
    const float* a2_dst = (const float*)d_in[9];
    const float* b2     = (const float*)d_in[10];
    const float* Wres2  = (const float*)d_in[11];
    const float* W3     = (const float*)d_in[12];
    const float* a3_src = (const float*)d_in[13];
    const float* a3_dst = (const float*)d_in[14];
    const float* b3     = (const float*)d_in[15];
    float* out = (float*)d_out;

    const int N = NODES, E = EDGES;
    const int EN = E + N;
    const int NB = (N + 255) / 256;  // 196

    char* p = (char*)d_ws;
    auto alloc = [&](size_t bytes) -> char* {
        char* r = p;
        p += (bytes + 511) & ~(size_t)511;
        return r;
    };
    // persistent
    int*   row_ptr = (int*)alloc((size_t)(N + 1) * sizeof(int));
    int*   cursor  = (int*)alloc((size_t)N * sizeof(int));
    int*   deg     = (int*)alloc((size_t)N * sizeof(int));
    int*   bsum    = (int*)alloc(256 * sizeof(int));
    int*   csr_src = (int*)alloc((size_t)EN * sizeof(int));
    float* alA     = (float*)alloc((size_t)N * 8 * sizeof(float));
    float* alB     = (float*)alloc((size_t)N * 8 * sizeof(float));
    float* al3     = (float*)alloc((size_t)N * 12 * sizeof(float));
    float* q1t     = (float*)alloc((size_t)8 * 128 * sizeof(float));
    float* q2t     = (float*)alloc((size_t)8 * 256 * sizeof(float));
    float* cm      = (float*)alloc((size_t)12 * 256 * sizeof(float));
    u16*   WT1     = (u16*)alloc((size_t)256 * 128 * sizeof(u16));
    u16*   WT2     = (u16*)alloc((size_t)512 * 256 * sizeof(u16));
    u16*   W3sT    = (u16*)alloc((size_t)128 * 1536 * sizeof(u16));
    u16*   o2b     = (u16*)alloc((size_t)MPAD * 256 * sizeof(u16));
    // region2 (phase-overlaid)
    const size_t A2B_B  = (size_t)MPAD * 256 * sizeof(u16);
    const size_t F1B_B  = (size_t)N * 256 * sizeof(u16);
    const size_t RESB_B = (size_t)N * 256 * sizeof(u16);
    const size_t S_B    = (size_t)C0 * 1536 * sizeof(u16);
    size_t r2_bytes = A2B_B + F1B_B + RESB_B;
    if (S_B > r2_bytes) r2_bytes = S_B;
    char* r2 = alloc(r2_bytes + 1024);
    u16* A2b  = (u16*)r2;                        // layer-1 out bf16 [MPAD,256]
    u16* f1b  = (u16*)(r2 + A2B_B);              // layer feat bf16 [N,256]
    u16* resb = (u16*)(r2 + A2B_B + F1B_B);      // layer-2 residual bf16 [N,256]
    u16* A2a  = (u16*)(r2 + A2B_B + F1B_B);      // x bf16 [MPAD,128] (dead before resb)
    u16* Sb   = (u16*)r2;                        // S chunk bf16 [C0,1536] (layer 3)
    (void)ws_size; (void)n_in; (void)in_sizes; (void)out_size;

    // --- CSR build ---
    fill_ones_kernel<<<NB, 256, 0, stream>>>(deg, N);
    hist_kernel<<<(E + 255) / 256, 256, 0, stream>>>(dst, deg, E);
    deg_bsum_kernel<<<NB, 256, 0, stream>>>(deg, bsum, N);
    bsum_scan_kernel<<<1, 256, 0, stream>>>(bsum, row_ptr, NB, N);
    deg_scan_kernel<<<NB, 256, 0, stream>>>(deg, bsum, row_ptr, cursor, N);
    scatter_kernel<<<(E + N + 255) / 256, 256, 0, stream>>>(src, dst, E, N, cursor, csr_src);

    int nwb = (N + 3) / 4;

    // --- all weight prep in one launch ---
    prep_weights<<<(PREP_TOTAL + 255) / 256, 256, 0, stream>>>(
        W1, W2, Wres2, W3, a1_src, a1_dst, a2_src, a2_dst, a3_src, a3_dst,
        WT1, WT2, W3sT, q1t, q2t, cm);

    // --- layer 1: 128 -> 4x64 concat, ELU ---
    convx_al1<<<nwb, 256, 0, stream>>>(x, q1t, A2a, alA, N);
    {
        dim3 g(MPAD / 128, 2);
        gemm_mfma_kernel<<<g, 256, 0, stream>>>(A2a, WT1, f1b, nullptr, N, 256, 128, 256, 9999);
    }
    agg4_fused<<<nwb, 256, 0, stream>>>(f1b, alA, row_ptr, csr_src, b1, nullptr, A2b,
                                        q2t, alB, nullptr, nullptr, N);

    // --- layer 2: 256 -> 4x64 concat + residual (one 512-wide GEMM), ELU ---
    {
        dim3 g(MPAD / 128, 4);
        gemm_mfma_kernel<<<g, 256, 0, stream>>>(A2b, WT2, f1b, resb, N, 512, 256, 256, 256);
    }
    agg4_fused<<<nwb, 256, 0, stream>>>(f1b, alB, row_ptr, csr_src, b2, resb, o2b,
                                        nullptr, nullptr, cm, al3, N);

    // --- layer 3: fused softmax+input-space agg -> skinny GEMM ---
    {
        aggS_fused<<<(C0 + 3) / 4, 256, 0, stream>>>(o2b, al3, row_ptr, csr_src, Sb, 0, C0);
        gemm_skinny64<<<(C0 + 63) / 64, 256, 0, stream>>>(Sb, W3sT, out, b3, C0);
        aggS_fused<<<(C1 + 3) / 4, 256, 0, stream>>>(o2b, al3, row_ptr, csr_src, Sb, C0, C1);
        gemm_skinny64<<<(C1 + 63) / 64, 256, 0, stream>>>(Sb, W3sT, out + (size_t)C0 * 121, b3, C1);
    }
}

// Round 10
// 669.175 us; speedup vs baseline: 1.0484x; 1.0359x over previous
//
#include <hip/hip_runtime.h>
#include <hip/hip_bf16.h>

// PPI GAT, 3 layers. N=50000, E=800000 (+N self loops), avg degree ~17.
// R8 (3rd submit; prior two hit MI355X container-acquisition failures):
// agg4_fused in lean R6 form (20 VGPR, high occupancy — R7's fused logit
// epilogue halved occupancy and doubled its time); logits via standalone
// row_logit8/12 q-vector kernels; R7's prep_weights, convx_al1,
// gemm_skinny64; R5-form aggS.

#define NODES 50000
#define EDGES 800000
#define MPAD  50048            // ceil(N/128)*128
#define C0    25088            // layer-3 chunk-0 rows
#define C1    24912            // layer-3 chunk-1 rows

typedef unsigned short u16;
typedef __attribute__((ext_vector_type(8))) short bf16x8;
typedef __attribute__((ext_vector_type(4))) float f32x4;

__device__ __forceinline__ float bf16f(u16 r) {
    return __uint_as_float(((unsigned)r) << 16);
}
__device__ __forceinline__ u16 f2b(float v) {
    __hip_bfloat16 b = __float2bfloat16(v);
    return *(u16*)&b;
}
__device__ __forceinline__ float blo(unsigned d) { return __uint_as_float(d << 16); }
__device__ __forceinline__ float bhi(unsigned d) { return __uint_as_float(d & 0xffff0000u); }

// ---------------- CSR build ----------------

__global__ void fill_ones_kernel(int* __restrict__ deg, int n) {
    int i = blockIdx.x * blockDim.x + threadIdx.x;
    if (i < n) deg[i] = 1;  // self-loop
}

__global__ void hist_kernel(const int* __restrict__ dst, int* __restrict__ deg, int E) {
    int e = blockIdx.x * blockDim.x + threadIdx.x;
    if (e < E) atomicAdd(&deg[dst[e]], 1);
}

__global__ void deg_bsum_kernel(const int* __restrict__ deg, int* __restrict__ bsum, int n) {
    int tid = threadIdx.x, lane = tid & 63, wid = tid >> 6;
    int i = blockIdx.x * 256 + tid;
    int v = (i < n) ? deg[i] : 0;
    #pragma unroll
    for (int ofs = 32; ofs > 0; ofs >>= 1) v += __shfl_down(v, ofs);
    __shared__ int sp[4];
    if (lane == 0) sp[wid] = v;
    __syncthreads();
    if (tid == 0) bsum[blockIdx.x] = sp[0] + sp[1] + sp[2] + sp[3];
}

__global__ void bsum_scan_kernel(int* __restrict__ bsum, int* __restrict__ row_ptr,
                                 int nb, int n) {
    int tid = threadIdx.x, lane = tid & 63, wid = tid >> 6;
    int v = (tid < nb) ? bsum[tid] : 0;
    int incl = v;
    #pragma unroll
    for (int ofs = 1; ofs < 64; ofs <<= 1) {
        int t = __shfl_up(incl, ofs);
        if (lane >= ofs) incl += t;
    }
    __shared__ int sp[4];
    if (lane == 63) sp[wid] = incl;
    __syncthreads();
    int add = 0;
    for (int k = 0; k < wid; k++) add += sp[k];
    int excl = incl - v + add;
    if (tid < nb) bsum[tid] = excl;
    if (tid == nb - 1) row_ptr[n] = excl + v;
}

__global__ void deg_scan_kernel(const int* __restrict__ deg, const int* __restrict__ bofs,
                                int* __restrict__ row_ptr, int* __restrict__ cursor, int n) {
    int tid = threadIdx.x, lane = tid & 63, wid = tid >> 6;
    int i = blockIdx.x * 256 + tid;
    int v = (i < n) ? deg[i] : 0;
    int incl = v;
    #pragma unroll
    for (int ofs = 1; ofs < 64; ofs <<= 1) {
        int t = __shfl_up(incl, ofs);
        if (lane >= ofs) incl += t;
    }
    __shared__ int sp[4];
    if (lane == 63) sp[wid] = incl;
    __syncthreads();
    int add = bofs[blockIdx.x];
    for (int k = 0; k < wid; k++) add += sp[k];
    int excl = incl - v + add;
    if (i < n) { row_ptr[i] = excl; cursor[i] = excl; }
}

__global__ void scatter_kernel(const int* __restrict__ src, const int* __restrict__ dst,
                               int E, int n, int* __restrict__ cursor, int* __restrict__ csr_src) {
    int e = blockIdx.x * blockDim.x + threadIdx.x;
    if (e < E) {
        int d = dst[e];
        int p = atomicAdd(&cursor[d], 1);
        csr_src[p] = src[e];
    } else if (e < E + n) {
        int i = e - E;
        int p = atomicAdd(&cursor[i], 1);
        csr_src[p] = i;  // self-loop
    }
}

// ---------------- prep: all weight converts + q-vectors, one launch ----------------

__global__ void prep_weights(
    const float* __restrict__ W1, const float* __restrict__ W2,
    const float* __restrict__ Wres2, const float* __restrict__ W3,
    const float* __restrict__ a1s, const float* __restrict__ a1d,
    const float* __restrict__ a2s, const float* __restrict__ a2d,
    const float* __restrict__ a3s, const float* __restrict__ a3d,
    u16* __restrict__ WT1, u16* __restrict__ WT2, u16* __restrict__ W3sT,
    float* __restrict__ q1t, float* __restrict__ q2t, float* __restrict__ cm) {
    int idx = blockIdx.x * 256 + threadIdx.x;
    if (idx < 32768) {                        // WT1
        int n = idx >> 7, k = idx & 127;
        WT1[idx] = f2b(W1[(size_t)k * 256 + n]);
    } else if ((idx -= 32768) < 131072) {     // WT2 = [W2 | Wres2]
        int n = idx >> 8, k = idx & 255;
        float v = (n < 256) ? W2[(size_t)k * 256 + n] : Wres2[(size_t)k * 256 + (n - 256)];
        WT2[idx] = f2b(v);
    } else if ((idx -= 131072) < 196608) {    // W3sT
        int n = idx / 1536, q = idx % 1536;
        int h = q >> 8, k = q & 255;
        W3sT[idx] = f2b((n < 121) ? W3[(size_t)k * 726 + h * 121 + n] : 0.f);
    } else if ((idx -= 196608) < 1024) {      // q1t
        int h = idx >> 7, k = idx & 127;
        int hh = h & 3;
        const float* a = (h < 4) ? a1s : a1d;
        float v = 0.f;
        for (int c = 0; c < 64; c++) v += W1[(size_t)k * 256 + hh * 64 + c] * a[hh * 64 + c];
        q1t[idx] = v;
    } else if ((idx -= 1024) < 2048) {        // q2t
        int h = idx >> 8, k = idx & 255;
        int hh = h & 3;
        const float* a = (h < 4) ? a2s : a2d;
        float v = 0.f;
        for (int c = 0; c < 64; c++) v += W2[(size_t)k * 256 + hh * 64 + c] * a[hh * 64 + c];
        q2t[idx] = v;
    } else if ((idx -= 2048) < 3072) {        // cm
        int o = idx >> 8, k = idx & 255;
        int h = (o < 6) ? o : o - 6;
        const float* a = (o < 6) ? a3s : a3d;
        float v = 0.f;
        for (int c = 0; c < 121; c++) v += W3[(size_t)k * 726 + h * 121 + c] * a[h * 121 + c];
        cm[idx] = v;
    }
}
#define PREP_TOTAL (32768 + 131072 + 196608 + 1024 + 2048 + 3072)

// ---------------- convx + layer-1 logits: wave per node ----------------

__global__ __launch_bounds__(256) void convx_al1(
    const float* __restrict__ x, const float* __restrict__ q1t,
    u16* __restrict__ A2a, float* __restrict__ alA, int n) {
    int wid = threadIdx.x >> 6, lane = threadIdx.x & 63;
    int i = blockIdx.x * 4 + wid;
    if (i >= n) return;
    float2 xv = *(const float2*)(x + (size_t)i * 128 + lane * 2);
    ushort2 o;
    o.x = f2b(xv.x); o.y = f2b(xv.y);
    *(ushort2*)(A2a + (size_t)i * 128 + lane * 2) = o;
    float p[8];
    #pragma unroll
    for (int h = 0; h < 8; h++) {
        float2 q = *(const float2*)(q1t + h * 128 + lane * 2);
        p[h] = xv.x * q.x + xv.y * q.y;
    }
    #pragma unroll
    for (int ofs = 1; ofs <= 32; ofs <<= 1) {
        #pragma unroll
        for (int h = 0; h < 8; h++) p[h] += __shfl_xor(p[h], ofs);
    }
    if (lane == 0) {
        *(float4*)(alA + (size_t)i * 8)     = make_float4(p[0], p[1], p[2], p[3]);
        *(float4*)(alA + (size_t)i * 8 + 4) = make_float4(p[4], p[5], p[6], p[7]);
    }
}

// ---------------- row logits from bf16 feature rows (wave per node) ----------------
// al[i*8+h] = row_i . q[h]   (q: [8][256] fp32)

__global__ __launch_bounds__(256) void row_logit8(
    const u16* __restrict__ f, const float* __restrict__ q,
    float* __restrict__ al, int n) {
    int wid = threadIdx.x >> 6, lane = threadIdx.x & 63;
    int i = blockIdx.x * 4 + wid;
    if (i >= n) return;
    uint2 d = *(const uint2*)(f + (size_t)i * 256 + lane * 4);
    float v0 = blo(d.x), v1 = bhi(d.x), v2 = blo(d.y), v3 = bhi(d.y);
    float p[8];
    #pragma unroll
    for (int h = 0; h < 8; h++) {
        float4 c = *(const float4*)(q + (size_t)h * 256 + lane * 4);
        p[h] = v0 * c.x + v1 * c.y + v2 * c.z + v3 * c.w;
    }
    #pragma unroll
    for (int ofs = 1; ofs <= 32; ofs <<= 1) {
        #pragma unroll
        for (int h = 0; h < 8; h++) p[h] += __shfl_xor(p[h], ofs);
    }
    if (lane == 0) {
        *(float4*)(al + (size_t)i * 8)     = make_float4(p[0], p[1], p[2], p[3]);
        *(float4*)(al + (size_t)i * 8 + 4) = make_float4(p[4], p[5], p[6], p[7]);
    }
}

__global__ __launch_bounds__(256) void row_logit12(
    const u16* __restrict__ f, const float* __restrict__ q,
    float* __restrict__ al, int n) {
    int wid = threadIdx.x >> 6, lane = threadIdx.x & 63;
    int i = blockIdx.x * 4 + wid;
    if (i >= n) return;
    uint2 d = *(const uint2*)(f + (size_t)i * 256 + lane * 4);
    float v0 = blo(d.x), v1 = bhi(d.x), v2 = blo(d.y), v3 = bhi(d.y);
    float p[12];
    #pragma unroll
    for (int h = 0; h < 12; h++) {
        float4 c = *(const float4*)(q + (size_t)h * 256 + lane * 4);
        p[h] = v0 * c.x + v1 * c.y + v2 * c.z + v3 * c.w;
    }
    #pragma unroll
    for (int ofs = 1; ofs <= 32; ofs <<= 1) {
        #pragma unroll
        for (int h = 0; h < 12; h++) p[h] += __shfl_xor(p[h], ofs);
    }
    if (lane == 0) {
        *(float4*)(al + (size_t)i * 12)     = make_float4(p[0], p[1], p[2], p[3]);
        *(float4*)(al + (size_t)i * 12 + 4) = make_float4(p[4], p[5], p[6], p[7]);
        *(float4*)(al + (size_t)i * 12 + 8) = make_float4(p[8], p[9], p[10], p[11]);
    }
}

// ---------------- bf16 MFMA GEMM (square-ish): C = A @ B^T, bf16 out, col split ----------------

__global__ __launch_bounds__(256) void gemm_mfma_kernel(
    const u16* __restrict__ A, const u16* __restrict__ B,
    u16* __restrict__ Cb, u16* __restrict__ Cb2,
    int M, int Ncols, int K2, int ldc, int split) {
    __shared__ __align__(16) u16 As[128][40];
    __shared__ __align__(16) u16 Bs[128][40];
    int tid = threadIdx.x;
    int lane = tid & 63;
    int wv = tid >> 6;
    int quad = lane >> 4, lm = lane & 15;
    int wm = (wv & 1) * 64, wn = (wv >> 1) * 64;
    int bm = blockIdx.x * 128, bn = blockIdx.y * 128;

    f32x4 zero = {0.f, 0.f, 0.f, 0.f};
    f32x4 acc[4][4];
    #pragma unroll
    for (int i = 0; i < 4; i++)
        #pragma unroll
        for (int j = 0; j < 4; j++) acc[i][j] = zero;

    for (int k0 = 0; k0 < K2; k0 += 32) {
        #pragma unroll
        for (int it = 0; it < 2; ++it) {
            int chunk = tid + it * 256;
            int row = chunk >> 2, seg = chunk & 3;
            uint4 va = *(const uint4*)(A + (size_t)(bm + row) * K2 + k0 + seg * 8);
            uint4 vb = *(const uint4*)(B + (size_t)(bn + row) * K2 + k0 + seg * 8);
            *(uint4*)&As[row][seg * 8] = va;
            *(uint4*)&Bs[row][seg * 8] = vb;
        }
        __syncthreads();
        bf16x8 af[4], bfr[4];
        #pragma unroll
        for (int i = 0; i < 4; i++) af[i] = *(const bf16x8*)&As[wm + i * 16 + lm][quad * 8];
        #pragma unroll
        for (int j = 0; j < 4; j++) bfr[j] = *(const bf16x8*)&Bs[wn + j * 16 + lm][quad * 8];
        #pragma unroll
        for (int i = 0; i < 4; i++)
            #pragma unroll
            for (int j = 0; j < 4; j++)
                acc[i][j] = __builtin_amdgcn_mfma_f32_16x16x32_bf16(af[i], bfr[j], acc[i][j], 0, 0, 0);
        __syncthreads();
    }

    // C/D layout: col = lane&15, row = quad*4 + reg
    #pragma unroll
    for (int i = 0; i < 4; i++) {
        #pragma unroll
        for (int j = 0; j < 4; j++) {
            int col = bn + wn + j * 16 + lm;
            if (col >= Ncols) continue;
            int row_base = bm + wm + i * 16 + quad * 4;
            #pragma unroll
            for (int r = 0; r < 4; r++) {
                int row = row_base + r;
                if (row >= M) continue;
                float v = acc[i][j][r];
                if (col < split) Cb[(size_t)row * ldc + col] = f2b(v);
                else             Cb2[(size_t)row * ldc + col - split] = f2b(v);
            }
        }
    }
}

// ---------------- skinny GEMM (layer 3): C[count,121] = A[count,1536] @ B[128,1536]^T ----

__global__ __launch_bounds__(256) void gemm_skinny64(
    const u16* __restrict__ A, const u16* __restrict__ B,
    float* __restrict__ C, const float* __restrict__ bias, int count) {
    __shared__ __align__(16) u16 As[64][40];
    __shared__ __align__(16) u16 Bs[128][40];
    int tid = threadIdx.x, lane = tid & 63, wv = tid >> 6;
    int quad = lane >> 4, lm = lane & 15;
    int bm = blockIdx.x * 64;
    int mrow = (wv >> 1) * 32, ncol = (wv & 1) * 64;
    int ar = bm + (tid >> 2);
    if (ar >= count) ar = count - 1;
    const u16* Ap = A + (size_t)ar * 1536 + (tid & 3) * 8;

    f32x4 zero = {0.f, 0.f, 0.f, 0.f};
    f32x4 acc[2][4];
    #pragma unroll
    for (int i = 0; i < 2; i++)
        #pragma unroll
        for (int j = 0; j < 4; j++) acc[i][j] = zero;

    for (int k0 = 0; k0 < 1536; k0 += 32) {
        *(uint4*)&As[tid >> 2][(tid & 3) * 8] = *(const uint4*)(Ap + k0);
        #pragma unroll
        for (int it = 0; it < 2; ++it) {
            int t = tid + it * 256;
            *(uint4*)&Bs[t >> 2][(t & 3) * 8] =
                *(const uint4*)(B + (size_t)(t >> 2) * 1536 + k0 + (t & 3) * 8);
        }
        __syncthreads();
        bf16x8 af[2], bfr[4];
        #pragma unroll
        for (int i = 0; i < 2; i++) af[i] = *(const bf16x8*)&As[mrow + i * 16 + lm][quad * 8];
        #pragma unroll
        for (int j = 0; j < 4; j++) bfr[j] = *(const bf16x8*)&Bs[ncol + j * 16 + lm][quad * 8];
        #pragma unroll
        for (int i = 0; i < 2; i++)
            #pragma unroll
            for (int j = 0; j < 4; j++)
                acc[i][j] = __builtin_amdgcn_mfma_f32_16x16x32_bf16(af[i], bfr[j], acc[i][j], 0, 0, 0);
        __syncthreads();
    }

    #pragma unroll
    for (int i = 0; i < 2; i++) {
        #pragma unroll
        for (int j = 0; j < 4; j++) {
            int col = ncol + j * 16 + lm;
            if (col >= 121) continue;
            int row_base = bm + mrow + i * 16 + quad * 4;
            #pragma unroll
            for (int r = 0; r < 4; r++) {
                int row = row_base + r;
                if (row >= count) continue;
                float v = acc[i][j][r] + bias[col];
                v = 1.f / (1.f + __expf(-v));
                C[(size_t)row * 121 + col] = v;
            }
        }
    }
}

// ---------------- fused softmax+agg, layers 1&2: WAVE per node (lean R6 form) ----------------
// al8 layout: [i][0..3]=src logits, [i][4..7]=dst logits.

__global__ __launch_bounds__(256) void agg4_fused(
    const u16* __restrict__ f, const float* __restrict__ al8,
    const int* __restrict__ row_ptr, const int* __restrict__ csr_src,
    const float* __restrict__ bias, const u16* __restrict__ resb,
    u16* __restrict__ outb, int n) {
    int wid = threadIdx.x >> 6, lane = threadIdx.x & 63;
    int i = blockIdx.x * 4 + wid;
    if (i >= n) return;
    int beg = row_ptr[i], end = row_ptr[i + 1];
    int h_st = lane >> 4;        // staging head
    int el = lane & 15;          // staging edge slot
    int half = lane >> 5;        // edge parity
    int c8 = (lane & 31) * 8;    // this lane's 8 channels
    float ald_st = al8[(size_t)i * 8 + 4 + h_st];
    float acc[8] = {};
    float S = 0.f;
    for (int base = beg; base < end; base += 16) {
        int cnt = min(16, end - base);
        int idxv = csr_src[base + min(el, cnt - 1)];
        float av = al8[(size_t)idxv * 8 + h_st] + ald_st;
        av = av > 0.f ? av : 0.2f * av;
        float ex = __expf(fminf(av, 60.f));
        for (int e = 0; e < cnt; e += 2) {
            int ei = e + half;
            int eu = ei < cnt ? ei : e;
            int s = __shfl(idxv, eu);
            float w = __shfl(ex, ((lane & 24) << 1) | eu);
            if (ei >= cnt) w = 0.f;
            S += w;
            uint4 d = *(const uint4*)(f + (size_t)s * 256 + c8);
            acc[0] = fmaf(w, blo(d.x), acc[0]); acc[1] = fmaf(w, bhi(d.x), acc[1]);
            acc[2] = fmaf(w, blo(d.y), acc[2]); acc[3] = fmaf(w, bhi(d.y), acc[3]);
            acc[4] = fmaf(w, blo(d.z), acc[4]); acc[5] = fmaf(w, bhi(d.z), acc[5]);
            acc[6] = fmaf(w, blo(d.w), acc[6]); acc[7] = fmaf(w, bhi(d.w), acc[7]);
        }
    }
    #pragma unroll
    for (int k = 0; k < 8; k++) acc[k] += __shfl_xor(acc[k], 32);
    S += __shfl_xor(S, 32);
    if (half == 0) {
        float inv = 1.f / (S + 1e-16f);
        float4 b0 = *(const float4*)(bias + c8);
        float4 b1 = *(const float4*)(bias + c8 + 4);
        float v[8];
        v[0] = acc[0] * inv + b0.x; v[1] = acc[1] * inv + b0.y;
        v[2] = acc[2] * inv + b0.z; v[3] = acc[3] * inv + b0.w;
        v[4] = acc[4] * inv + b1.x; v[5] = acc[5] * inv + b1.y;
        v[6] = acc[6] * inv + b1.z; v[7] = acc[7] * inv + b1.w;
        if (resb) {
            uint4 r = *(const uint4*)(resb + (size_t)i * 256 + c8);
            v[0] += blo(r.x); v[1] += bhi(r.x); v[2] += blo(r.y); v[3] += bhi(r.y);
            v[4] += blo(r.z); v[5] += bhi(r.z); v[6] += blo(r.w); v[7] += bhi(r.w);
        }
        #pragma unroll
        for (int k = 0; k < 8; k++) v[k] = v[k] > 0.f ? v[k] : (__expf(v[k]) - 1.f);  // ELU
        uint4 o;
        o.x = (unsigned)f2b(v[0]) | ((unsigned)f2b(v[1]) << 16);
        o.y = (unsigned)f2b(v[2]) | ((unsigned)f2b(v[3]) << 16);
        o.z = (unsigned)f2b(v[4]) | ((unsigned)f2b(v[5]) << 16);
        o.w = (unsigned)f2b(v[6]) | ((unsigned)f2b(v[7]) << 16);
        *(uint4*)(outb + (size_t)i * 256 + c8) = o;
    }
}

// ---------------- fused softmax+agg, layer 3 (6 heads): WAVE per node (R5 form) ----------------

__global__ __launch_bounds__(256) void aggS_fused(
    const u16* __restrict__ x, const float* __restrict__ al3,
    const int* __restrict__ row_ptr, const int* __restrict__ csr_src,
    u16* __restrict__ S, int node0, int count) {
    __shared__ int s_i[4][16];
    __shared__ float s_w[4][96];
    int wid = threadIdx.x >> 6, lane = threadIdx.x & 63;
    int li = blockIdx.x * 4 + wid;
    if (li >= count) return;
    int i = node0 + li;
    int beg = row_ptr[i], end = row_ptr[i + 1];
    int c4 = lane * 4;
    int e16 = lane & 15;
    int hA = lane >> 4;            // heads 0-3 staging
    int hB = 4 + (lane >> 4);      // heads 4-5 staging (lanes 0-31)
    float aldA = al3[(size_t)i * 12 + 6 + hA];
    float aldB = (lane < 32) ? al3[(size_t)i * 12 + 6 + hB] : 0.f;
    float acc[6][4] = {};
    float Ssum[6] = {};
    for (int base = beg; base < end; base += 16) {
        int cnt = min(16, end - base);
        int idxe = csr_src[base + min(e16, cnt - 1)];
        if (lane < 16) s_i[wid][lane] = idxe;
        float vA = al3[(size_t)idxe * 12 + hA] + aldA;
        vA = vA > 0.f ? vA : 0.2f * vA;
        float exA = __expf(fminf(vA, 60.f));
        if (e16 < cnt) s_w[wid][e16 * 6 + hA] = exA;
        if (lane < 32) {
            float vB = al3[(size_t)idxe * 12 + hB] + aldB;
            vB = vB > 0.f ? vB : 0.2f * vB;
            float exB = __expf(fminf(vB, 60.f));
            if (e16 < cnt) s_w[wid][e16 * 6 + hB] = exB;
        }
        // wave-coherent LDS (lockstep), no barrier
        for (int e = 0; e < cnt; e++) {
            int s = s_i[wid][e];
            uint2 d = *(const uint2*)(x + (size_t)s * 256 + c4);
            float v0 = blo(d.x), v1 = bhi(d.x), v2 = blo(d.y), v3 = bhi(d.y);
            #pragma unroll
            for (int hh = 0; hh < 6; hh++) {
                float w = s_w[wid][e * 6 + hh];
                Ssum[hh] += w;
                acc[hh][0] = fmaf(w, v0, acc[hh][0]);
                acc[hh][1] = fmaf(w, v1, acc[hh][1]);
                acc[hh][2] = fmaf(w, v2, acc[hh][2]);
                acc[hh][3] = fmaf(w, v3, acc[hh][3]);
            }
        }
    }
    #pragma unroll
    for (int hh = 0; hh < 6; hh++) {
        float inv = 1.f / (6.f * (Ssum[hh] + 1e-16f));
        ushort4 o;
        o.x = f2b(acc[hh][0] * inv);
        o.y = f2b(acc[hh][1] * inv);
        o.z = f2b(acc[hh][2] * inv);
        o.w = f2b(acc[hh][3] * inv);
        *(ushort4*)(S + (size_t)li * 1536 + hh * 256 + c4) = o;
    }
}

// ---------------- host ----------------

extern "C" void kernel_launch(void* const* d_in, const int* in_sizes, int n_in,
                              void* d_out, int out_size, void* d_ws, size_t ws_size,
                              hipStream_t stream) {
    const float* x      = (const float*)d_in[0];
    const int*   src    = (const int*)d_in[1];
    const int*   dst    = (const int*)d_in[2];
    const float* W1     = (const float*)d_in[3];
    const float* a1_src = (const float*)d_in[4];
    const float* a1_dst = (const float*)d_in[5];
    const float* b1     = (const float*)d_in[6];
    const float* W2     = (const float*)d_in[7];
    const float* a2_src = (const float*)d_in[8];
    const float* a2_dst = (const float*)d_in[9];
    const float* b2     = (const float*)d_in[10];
    const float* Wres2  = (const float*)d_in[11];
    const float* W3     = (const float*)d_in[12];
    const float* a3_src = (const float*)d_in[13];
    const float* a3_dst = (const float*)d_in[14];
    const float* b3     = (const float*)d_in[15];
    float* out = (float*)d_out;

    const int N = NODES, E = EDGES;
    const int EN = E + N;
    const int NB = (N + 255) / 256;  // 196

    char* p = (char*)d_ws;
    auto alloc = [&](size_t bytes) -> char* {
        char* r = p;
        p += (bytes + 511) & ~(size_t)511;
        return r;
    };
    // persistent
    int*   row_ptr = (int*)alloc((size_t)(N + 1) * sizeof(int));
    int*   cursor  = (int*)alloc((size_t)N * sizeof(int));
    int*   deg     = (int*)alloc((size_t)N * sizeof(int));
    int*   bsum    = (int*)alloc(256 * sizeof(int));
    int*   csr_src = (int*)alloc((size_t)EN * sizeof(int));
    float* alA     = (float*)alloc((size_t)N * 8 * sizeof(float));
    float* alB     = (float*)alloc((size_t)N * 8 * sizeof(float));
    float* al3     = (float*)alloc((size_t)N * 12 * sizeof(float));
    float* q1t     = (float*)alloc((size_t)8 * 128 * sizeof(float));
    float* q2t     = (float*)alloc((size_t)8 * 256 * sizeof(float));
    float* cm      = (float*)alloc((size_t)12 * 256 * sizeof(float));
    u16*   WT1     = (u16*)alloc((size_t)256 * 128 * sizeof(u16));
    u16*   WT2     = (u16*)alloc((size_t)512 * 256 * sizeof(u16));
    u16*   W3sT    = (u16*)alloc((size_t)128 * 1536 * sizeof(u16));
    u16*   o2b     = (u16*)alloc((size_t)MPAD * 256 * sizeof(u16));
    // region2 (phase-overlaid)
    const size_t A2B_B  = (size_t)MPAD * 256 * sizeof(u16);
    const size_t F1B_B  = (size_t)N * 256 * sizeof(u16);
    const size_t RESB_B = (size_t)N * 256 * sizeof(u16);
    const size_t S_B    = (size_t)C0 * 1536 * sizeof(u16);
    size_t r2_bytes = A2B_B + F1B_B + RESB_B;
    if (S_B > r2_bytes) r2_bytes = S_B;
    char* r2 = alloc(r2_bytes + 1024);
    u16* A2b  = (u16*)r2;                        // layer-1 out bf16 [MPAD,256]
    u16* f1b  = (u16*)(r2 + A2B_B);              // layer feat bf16 [N,256]
    u16* resb = (u16*)(r2 + A2B_B + F1B_B);      // layer-2 residual bf16 [N,256]
    u16* A2a  = (u16*)(r2 + A2B_B + F1B_B);      // x bf16 [MPAD,128] (dead before resb)
    u16* Sb   = (u16*)r2;                        // S chunk bf16 [C0,1536] (layer 3)
    (void)ws_size; (void)n_in; (void)in_sizes; (void)out_size;

    // --- CSR build ---
    fill_ones_kernel<<<NB, 256, 0, stream>>>(deg, N);
    hist_kernel<<<(E + 255) / 256, 256, 0, stream>>>(dst, deg, E);
    deg_bsum_kernel<<<NB, 256, 0, stream>>>(deg, bsum, N);
    bsum_scan_kernel<<<1, 256, 0, stream>>>(bsum, row_ptr, NB, N);
    deg_scan_kernel<<<NB, 256, 0, stream>>>(deg, bsum, row_ptr, cursor, N);
    scatter_kernel<<<(E + N + 255) / 256, 256, 0, stream>>>(src, dst, E, N, cursor, csr_src);

    int nwb = (N + 3) / 4;

    // --- all weight prep in one launch ---
    prep_weights<<<(PREP_TOTAL + 255) / 256, 256, 0, stream>>>(
        W1, W2, Wres2, W3, a1_src, a1_dst, a2_src, a2_dst, a3_src, a3_dst,
        WT1, WT2, W3sT, q1t, q2t, cm);

    // --- layer 1: 128 -> 4x64 concat, ELU ---
    convx_al1<<<nwb, 256, 0, stream>>>(x, q1t, A2a, alA, N);
    {
        dim3 g(MPAD / 128, 2);
        gemm_mfma_kernel<<<g, 256, 0, stream>>>(A2a, WT1, f1b, nullptr, N, 256, 128, 256, 9999);
    }
    agg4_fused<<<nwb, 256, 0, stream>>>(f1b, alA, row_ptr, csr_src, b1, nullptr, A2b, N);
    row_logit8<<<nwb, 256, 0, stream>>>(A2b, q2t, alB, N);

    // --- layer 2: 256 -> 4x64 concat + residual (one 512-wide GEMM), ELU ---
    {
        dim3 g(MPAD / 128, 4);
        gemm_mfma_kernel<<<g, 256, 0, stream>>>(A2b, WT2, f1b, resb, N, 512, 256, 256, 256);
    }
    agg4_fused<<<nwb, 256, 0, stream>>>(f1b, alB, row_ptr, csr_src, b2, resb, o2b, N);
    row_logit12<<<nwb, 256, 0, stream>>>(o2b, cm, al3, N);

    // --- layer 3: fused softmax+input-space agg -> skinny GEMM ---
    {
        aggS_fused<<<(C0 + 3) / 4, 256, 0, stream>>>(o2b, al3, row_ptr, csr_src, Sb, 0, C0);
        gemm_skinny64<<<(C0 + 63) / 64, 256, 0, stream>>>(Sb, W3sT, out, b3, C0);
        aggS_fused<<<(C1 + 3) / 4, 256, 0, stream>>>(o2b, al3, row_ptr, csr_src, Sb, C0, C1);
        gemm_skinny64<<<(C1 + 63) / 64, 256, 0, stream>>>(Sb, W3sT, out + (size_t)C0 * 121, b3, C1);
    }
}